// Round 6
// baseline (1261.657 us; speedup 1.0000x reference)
//
#include <hip/hip_runtime.h>
#include <hip/hip_bf16.h>

// ---------------------------------------------------------------------------
// GINE 2-layer GNN, MI355X (gfx950)  — round 6
//   t[n] = sum_{e: dst=n} relu(x[src]+ea_e)@W1^T  +  (x@W1^T + b1)
// Changes vs R5 (latency-bound; one tile per wave = nothing to pipeline):
//  1. Persistent edge kernels: each wave loops over ~13-16 tiles.
//  2. Explicit 2-stage prefetch with named A/B register sets (2-body
//     unrolled loop; static indices only). Next tile's {se,sp,eattr}
//     issued before current compute; x-gather for next tile issued
//     mid-iteration (hides under GEMM2 + next GEMM1).
//  3. x-gather vectorized: add x at the A2 (post-transpose) phase where
//     lane (g,c) needs CONTIGUOUS x[src(c)][kk*32+g*8..] -> f32x4 loads
//     (8 instead of 32 scalar dwords); LDS holds (ea+be) pre-relu.
// ---------------------------------------------------------------------------

typedef short short8 __attribute__((ext_vector_type(8)));
typedef float f32x4 __attribute__((ext_vector_type(4)));

__device__ __forceinline__ short f2bf(float x) {
    unsigned u = __float_as_uint(x);
    unsigned r = (u + 0x7fffu + ((u >> 16) & 1u)) >> 16;   // RTNE
    return (short)r;
}
__device__ __forceinline__ float bf2f(unsigned short u) {
    return __uint_as_float(((unsigned)u) << 16);
}

// ---------------------------------------------------------------------------
// Counting sort of edges by dst -> inv (edge id -> sorted pos), offs (CSR)
// ---------------------------------------------------------------------------
__global__ __launch_bounds__(256) void hist_kernel(
    const int* __restrict__ ei, int* __restrict__ cnt, int E)
{
    int e = blockIdx.x * 256 + threadIdx.x;
    if (e < E) atomicAdd(&cnt[ei[E + e]], 1);
}

__global__ __launch_bounds__(1024) void scan_kernel(
    const int* __restrict__ cnt, int* __restrict__ offs,
    int* __restrict__ cursor, int N)
{
    __shared__ int wsum[16];
    __shared__ int chunk_base;
    int tid = threadIdx.x;
    int lane = tid & 63, wid = tid >> 6;
    if (tid == 0) chunk_base = 0;
    __syncthreads();
    for (int start = 0; start < N; start += 1024) {
        int i = start + tid;
        int v = (i < N) ? cnt[i] : 0;
        int s = v;
#pragma unroll
        for (int d = 1; d < 64; d <<= 1) {
            int t = __shfl_up(s, d);
            if (lane >= d) s += t;
        }
        if (lane == 63) wsum[wid] = s;
        __syncthreads();
        int wbase = 0;
        for (int w = 0; w < wid; ++w) wbase += wsum[w];
        int excl = chunk_base + wbase + s - v;
        if (i < N) { offs[i] = excl; cursor[i] = excl; }
        int tot = 0;
        for (int w = 0; w < 16; ++w) tot += wsum[w];
        __syncthreads();
        if (tid == 0) chunk_base += tot;
        __syncthreads();
    }
    if (threadIdx.x == 0) offs[N] = chunk_base;
}

__global__ __launch_bounds__(256) void scatter_kernel(
    const int* __restrict__ ei, int* __restrict__ cursor,
    int* __restrict__ inv, int E)
{
    int e = blockIdx.x * 256 + threadIdx.x;
    if (e >= E) return;
    int d = ei[E + e];
    int pos = atomicAdd(&cursor[d], 1);
    inv[e] = pos;
}

// ---------------------------------------------------------------------------
// Shared device helpers for the edge kernels
// ---------------------------------------------------------------------------
template<int DIN>
__device__ __forceinline__ void gemm1_to_lds(
    const f32x4 (&a)[4], const short* __restrict__ WeB,
    const float* __restrict__ be, short* myl, int g, int c)
{
    constexpr int S = DIN + 8;
    short8 afr0, afr1;
    afr0[0]=f2bf(a[0][0]); afr0[1]=f2bf(a[0][1]); afr0[2]=f2bf(a[0][2]); afr0[3]=f2bf(a[0][3]);
    afr0[4]=f2bf(a[1][0]); afr0[5]=f2bf(a[1][1]); afr0[6]=f2bf(a[1][2]); afr0[7]=f2bf(a[1][3]);
    afr1[0]=f2bf(a[2][0]); afr1[1]=f2bf(a[2][1]); afr1[2]=f2bf(a[2][2]); afr1[3]=f2bf(a[2][3]);
    afr1[4]=f2bf(a[3][0]); afr1[5]=f2bf(a[3][1]); afr1[6]=f2bf(a[3][2]); afr1[7]=f2bf(a[3][3]);
    // prior iteration's LDS reads must be complete before overwrite
    asm volatile("s_waitcnt lgkmcnt(0)" ::: "memory");
#pragma unroll
    for (int fc = 0; fc < DIN / 16; ++fc) {
        const short* brow = WeB + (size_t)(fc * 16 + c) * 64 + g * 8;
        short8 b0 = *(const short8*)(brow);
        short8 b1 = *(const short8*)(brow + 32);
        f32x4 acc = {0.f, 0.f, 0.f, 0.f};
        acc = __builtin_amdgcn_mfma_f32_16x16x32_bf16(afr0, b0, acc, 0, 0, 0);
        acc = __builtin_amdgcn_mfma_f32_16x16x32_bf16(afr1, b1, acc, 0, 0, 0);
        const int f = fc * 16 + c;
        const float bev = be[f];
#pragma unroll
        for (int r = 0; r < 4; ++r)
            myl[(g * 4 + r) * S + f] = f2bf(acc[r] + bev);   // pre-relu, pre-x
    }
}

template<int DIN>
__device__ __forceinline__ void gemm2_store(
    const f32x4 (&xv)[DIN / 16], const int (&sp)[4],
    const short* __restrict__ W1B, const short* myl,
    unsigned short* __restrict__ pbuf, int g, int c)
{
    constexpr int S = DIN + 8;
    constexpr int KK = DIN / 32;
    asm volatile("s_waitcnt lgkmcnt(0)" ::: "memory");
    __builtin_amdgcn_sched_barrier(0);
    short8 a2[KK];
#pragma unroll
    for (int kk = 0; kk < KK; ++kk) {
        short8 v = *(const short8*)(myl + c * S + kk * 32 + g * 8);
#pragma unroll
        for (int j = 0; j < 8; ++j) {
            float f = bf2f((unsigned short)v[j]) + xv[2 * kk + (j >> 2)][j & 3];
            a2[kk][j] = f2bf(fmaxf(f, 0.f));
        }
    }
#pragma unroll
    for (int cc = 0; cc < 4; ++cc) {
        f32x4 acc2 = {0.f, 0.f, 0.f, 0.f};
#pragma unroll
        for (int kk = 0; kk < KK; ++kk) {
            short8 b0 = *(const short8*)(W1B + (size_t)(cc * 16 + c) * DIN + kk * 32 + g * 8);
            acc2 = __builtin_amdgcn_mfma_f32_16x16x32_bf16(a2[kk], b0, acc2, 0, 0, 0);
        }
#pragma unroll
        for (int r = 0; r < 4; ++r)
            if (sp[r] >= 0)
                pbuf[(size_t)sp[r] * 64 + cc * 16 + c] = (unsigned short)f2bf(acc2[r]);
    }
}

// ---------------------------------------------------------------------------
// L0 edge kernel (DIN=128): persistent waves, 2-stage prefetch.
// ---------------------------------------------------------------------------
template<int DIN>
__global__ __launch_bounds__(256, 3) void edge2_kernel(
    const float*  __restrict__ x,
    const int*    __restrict__ ei,
    const float*  __restrict__ eattr,
    const short*  __restrict__ WeB,
    const float*  __restrict__ be,
    const short*  __restrict__ W1B,
    const int*    __restrict__ inv,
    unsigned short* __restrict__ pbuf,
    int E, int NT, int TW)
{
    constexpr int S = DIN + 8;
    constexpr int NX = DIN / 16;
    __shared__ short lds[4][16][S];
    const int wave = threadIdx.x >> 6;
    const int lane = threadIdx.x & 63;
    const int g = lane >> 4, c = lane & 15;
    short* myl = &lds[wave][0][0];
    const int wgid = blockIdx.x * 4 + wave;
    if (wgid >= NT) return;

    f32x4 aA[4], aB[4], xA[NX], xB[NX];
    int seA, seB, spA[4], spB[4];

    auto issue_tile = [&](int t, f32x4 (&a)[4], int& se, int (&sp)[4]) {
        int ce = t * 16 + c; if (ce >= E) ce = E - 1;
        se = ei[ce];
#pragma unroll
        for (int r = 0; r < 4; ++r) {
            int e = t * 16 + g * 4 + r;
            sp[r] = (e < E) ? inv[e] : -1;
        }
        const float* ar = eattr + (size_t)ce * 64 + g * 8;
        a[0] = *(const f32x4*)(ar);
        a[1] = *(const f32x4*)(ar + 4);
        a[2] = *(const f32x4*)(ar + 32);
        a[3] = *(const f32x4*)(ar + 36);
    };
    auto issue_x = [&](int se, f32x4 (&xv)[NX]) {
        const float* xr = x + (size_t)se * DIN + g * 8;
#pragma unroll
        for (int kk = 0; kk < DIN / 32; ++kk) {
            xv[2 * kk]     = *(const f32x4*)(xr + kk * 32);
            xv[2 * kk + 1] = *(const f32x4*)(xr + kk * 32 + 4);
        }
    };

    int t = wgid;
    issue_tile(t, aA, seA, spA);
    issue_x(seA, xA);
    for (;;) {
        int tn = t + TW; bool hn = tn < NT;
        issue_tile(hn ? tn : t, aB, seB, spB);
        __builtin_amdgcn_sched_barrier(0);
        gemm1_to_lds<DIN>(aA, WeB, be, myl, g, c);
        issue_x(seB, xB);
        gemm2_store<DIN>(xA, spA, W1B, myl, pbuf, g, c);
        if (!hn) break;
        t = tn;

        tn = t + TW; hn = tn < NT;
        issue_tile(hn ? tn : t, aA, seA, spA);
        __builtin_amdgcn_sched_barrier(0);
        gemm1_to_lds<DIN>(aB, WeB, be, myl, g, c);
        issue_x(seA, xA);
        gemm2_store<DIN>(xB, spB, W1B, myl, pbuf, g, c);
        if (!hn) break;
        t = tn;
    }
}

// ---------------------------------------------------------------------------
// L1 edge kernel (DIN=64, no GEMM2): persistent + prefetch.
// m = relu(y0[src] + ea + be) stored bf16 at sorted row inv[e].
// ---------------------------------------------------------------------------
__global__ __launch_bounds__(256, 4) void edge1_kernel(
    const float*  __restrict__ x,      // y0 [N][64]
    const int*    __restrict__ ei,
    const float*  __restrict__ eattr,
    const short*  __restrict__ WeB,
    const float*  __restrict__ be,
    const int*    __restrict__ inv,
    unsigned short* __restrict__ pbuf,
    int E, int NT, int TW)
{
    constexpr int S = 72;
    __shared__ short lds[4][16][S];
    const int wave = threadIdx.x >> 6;
    const int lane = threadIdx.x & 63;
    const int g = lane >> 4, c = lane & 15;
    short* myl = &lds[wave][0][0];
    const int wgid = blockIdx.x * 4 + wave;
    if (wgid >= NT) return;

    f32x4 aA[4], aB[4], xA[4], xB[4];
    int seA, seB, spA, spB;

    auto issue_tile = [&](int t, f32x4 (&a)[4], int& se, int& sp) {
        int ce = t * 16 + c;
        bool v = ce < E;
        if (!v) ce = E - 1;
        se = ei[ce];
        sp = v ? inv[ce] : -1;
        const float* ar = eattr + (size_t)ce * 64 + g * 8;
        a[0] = *(const f32x4*)(ar);
        a[1] = *(const f32x4*)(ar + 4);
        a[2] = *(const f32x4*)(ar + 32);
        a[3] = *(const f32x4*)(ar + 36);
    };
    auto issue_x = [&](int se, f32x4 (&xv)[4]) {
        const float* xr = x + (size_t)se * 64 + g * 8;
        xv[0] = *(const f32x4*)(xr);
        xv[1] = *(const f32x4*)(xr + 4);
        xv[2] = *(const f32x4*)(xr + 32);
        xv[3] = *(const f32x4*)(xr + 36);
    };
    auto store1 = [&](const f32x4 (&xv)[4], int spc) {
        asm volatile("s_waitcnt lgkmcnt(0)" ::: "memory");
        __builtin_amdgcn_sched_barrier(0);
        short8 out0, out1;
        short8 v0 = *(const short8*)(myl + c * S + g * 8);
        short8 v1 = *(const short8*)(myl + c * S + 32 + g * 8);
#pragma unroll
        for (int j = 0; j < 8; ++j) {
            float f0 = bf2f((unsigned short)v0[j]) + xv[j >> 2][j & 3];
            out0[j] = f2bf(fmaxf(f0, 0.f));
            float f1 = bf2f((unsigned short)v1[j]) + xv[2 + (j >> 2)][j & 3];
            out1[j] = f2bf(fmaxf(f1, 0.f));
        }
        if (spc >= 0) {
            *(short8*)(pbuf + (size_t)spc * 64 + g * 8) = out0;
            *(short8*)(pbuf + (size_t)spc * 64 + 32 + g * 8) = out1;
        }
    };

    int t = wgid;
    issue_tile(t, aA, seA, spA);
    issue_x(seA, xA);
    for (;;) {
        int tn = t + TW; bool hn = tn < NT;
        issue_tile(hn ? tn : t, aB, seB, spB);
        __builtin_amdgcn_sched_barrier(0);
        gemm1_to_lds<64>(aA, WeB, be, myl, g, c);
        issue_x(seB, xB);
        store1(xA, spA);
        if (!hn) break;
        t = tn;

        tn = t + TW; hn = tn < NT;
        issue_tile(hn ? tn : t, aA, seA, spA);
        __builtin_amdgcn_sched_barrier(0);
        gemm1_to_lds<64>(aB, WeB, be, myl, g, c);
        issue_x(seA, xA);
        store1(xB, spB);
        if (!hn) break;
        t = tn;
    }
}

// ---------------------------------------------------------------------------
// L0 gather (fused dense xw1): wave per node, lane = out feature f.
// ---------------------------------------------------------------------------
template<int DIN>
__global__ __launch_bounds__(256) void gather_kernel(
    const unsigned short* __restrict__ pbuf,
    const int* __restrict__ offs,
    const float* __restrict__ x, const float* __restrict__ W1,
    const float* __restrict__ b1, float* __restrict__ t, int N)
{
    int wid = threadIdx.x >> 6, lane = threadIdx.x & 63;
    int n = blockIdx.x * 4 + wid;
    if (n >= N) return;

    const f32x4* xr = (const f32x4*)(x + (size_t)n * DIN);
    const f32x4* wr = (const f32x4*)(W1 + (size_t)lane * DIN);
    float acc = b1[lane];
#pragma unroll
    for (int k = 0; k < DIN / 4; ++k) {
        f32x4 xx = xr[k], w = wr[k];
        acc += xx[0] * w[0] + xx[1] * w[1] + xx[2] * w[2] + xx[3] * w[3];
    }

    int i0 = offs[n], i1 = offs[n + 1];
    const unsigned short* p = pbuf + (size_t)i0 * 64 + lane;
    int cnt = i1 - i0;
    int i = 0;
    for (; i + 3 < cnt; i += 4) {
        acc += bf2f(p[0]) + bf2f(p[64]) + bf2f(p[128]) + bf2f(p[192]);
        p += 256;
    }
    for (; i < cnt; ++i) { acc += bf2f(p[0]); p += 64; }
    t[(size_t)n * 64 + lane] = acc;
}

// ---------------------------------------------------------------------------
// L1 gather + node-level W1 apply (f32 exact)
// ---------------------------------------------------------------------------
__global__ __launch_bounds__(256) void gather1_kernel(
    const unsigned short* __restrict__ pbuf,
    const int* __restrict__ offs,
    const float* __restrict__ y0, const float* __restrict__ W1,
    const float* __restrict__ b1, float* __restrict__ t, int N)
{
    __shared__ __align__(16) float sm[4][64];
    int wid = threadIdx.x >> 6, lane = threadIdx.x & 63;
    int n = blockIdx.x * 4 + wid;
    if (n >= N) return;

    int i0 = offs[n], i1 = offs[n + 1];
    float s = y0[(size_t)n * 64 + lane];
    const unsigned short* p = pbuf + (size_t)i0 * 64 + lane;
    int cnt = i1 - i0;
    int i = 0;
    for (; i + 3 < cnt; i += 4) {
        s += bf2f(p[0]) + bf2f(p[64]) + bf2f(p[128]) + bf2f(p[192]);
        p += 256;
    }
    for (; i < cnt; ++i) { s += bf2f(p[0]); p += 64; }
    sm[wid][lane] = s;

    asm volatile("s_waitcnt lgkmcnt(0)" ::: "memory");
    __builtin_amdgcn_sched_barrier(0);

    const f32x4* wr = (const f32x4*)(W1 + (size_t)lane * 64);
    const f32x4* sr = (const f32x4*)(sm[wid]);
    float acc = b1[lane];
#pragma unroll
    for (int kk = 0; kk < 16; ++kk) {
        f32x4 w = wr[kk], ss = sr[kk];
        acc += ss[0] * w[0] + ss[1] * w[1] + ss[2] * w[2] + ss[3] * w[3];
    }
    t[(size_t)n * 64 + lane] = acc;
}

// ---------------------------------------------------------------------------
// BN stats + final
// ---------------------------------------------------------------------------
__global__ __launch_bounds__(256) void bnstats_kernel(
    const float* __restrict__ t, float* __restrict__ sums, int total)
{
    int tid = threadIdx.x;
    float s = 0.f, s2 = 0.f;
    for (int i = blockIdx.x * 256 + tid; i < total; i += gridDim.x * 256) {
        float v = t[i];
        s += v; s2 += v * v;
    }
    __shared__ float ls[256], ls2[256];
    ls[tid] = s; ls2[tid] = s2;
    __syncthreads();
    if (tid < 64) {
        s  = ls[tid]  + ls[tid + 64]  + ls[tid + 128]  + ls[tid + 192];
        s2 = ls2[tid] + ls2[tid + 64] + ls2[tid + 128] + ls2[tid + 192];
        atomicAdd(&sums[tid], s);
        atomicAdd(&sums[64 + tid], s2);
    }
}

__global__ void bnfinal_kernel(const float* __restrict__ sums,
                               const float* __restrict__ g,
                               const float* __restrict__ bb,
                               float* __restrict__ scsh, float invN)
{
    int f = threadIdx.x;  // 64 threads
    float mean = sums[f] * invN;
    float var  = sums[64 + f] * invN - mean * mean;
    float sc = g[f] * rsqrtf(var + 1e-5f);
    scsh[f] = sc;
    scsh[64 + f] = bb[f] - mean * sc;
}

// ---------------------------------------------------------------------------
// mlp2: h = relu(t*scale+shift); out = h @ W2^T + b2 (+optional relu)
// ---------------------------------------------------------------------------
__global__ __launch_bounds__(256) void mlp2_kernel(
    const float* __restrict__ t, const float* __restrict__ scsh,
    const float* __restrict__ W2, const float* __restrict__ b2,
    float* __restrict__ out, int N, int relu_out)
{
    __shared__ __align__(16) float hs[4][64];
    int tid = threadIdx.x;
    int nl = tid >> 6, k = tid & 63;
    int n = blockIdx.x * 4 + nl;
    float h = 0.f;
    if (n < N) h = fmaxf(t[(size_t)n * 64 + k] * scsh[k] + scsh[64 + k], 0.f);
    hs[nl][k] = h;
    __syncthreads();
    if (n >= N) return;
    const int f = k;
    const f32x4* wr = (const f32x4*)(W2 + (size_t)f * 64);
    const f32x4* hr = (const f32x4*)(hs[nl]);
    float acc = b2[f];
#pragma unroll
    for (int kk = 0; kk < 16; ++kk) {
        f32x4 w = wr[kk], hh = hr[kk];
        acc += hh[0] * w[0] + hh[1] * w[1] + hh[2] * w[2] + hh[3] * w[3];
    }
    if (relu_out) acc = fmaxf(acc, 0.f);
    out[(size_t)n * 64 + f] = acc;
}

// ---------------------------------------------------------------------------
// Weight prep: f32 -> bf16
// ---------------------------------------------------------------------------
__global__ __launch_bounds__(256) void prep_kernel(
    const float* __restrict__ We0, const float* __restrict__ W1_0,
    const float* __restrict__ We1,
    short* __restrict__ WeB0, short* __restrict__ W1B0,
    short* __restrict__ WeB1)
{
    int i = blockIdx.x * 256 + threadIdx.x;
    if (i < 128 * 64) WeB0[i] = f2bf(We0[i]);
    if (i < 64 * 128) W1B0[i] = f2bf(W1_0[i]);
    if (i < 64 * 64)  WeB1[i] = f2bf(We1[i]);
}

extern "C" void kernel_launch(void* const* d_in, const int* in_sizes, int n_in,
                              void* d_out, int out_size, void* d_ws, size_t ws_size,
                              hipStream_t stream)
{
    (void)n_in; (void)out_size; (void)ws_size;
    const float* x     = (const float*)d_in[0];
    const int*   ei    = (const int*)d_in[1];
    const float* eattr = (const float*)d_in[2];
    const float* We0   = (const float*)d_in[3];
    const float* be0   = (const float*)d_in[4];
    const float* W1_0  = (const float*)d_in[5];
    const float* b1_0  = (const float*)d_in[6];
    const float* g0    = (const float*)d_in[7];
    const float* bb0   = (const float*)d_in[8];
    const float* W2_0  = (const float*)d_in[9];
    const float* b2_0  = (const float*)d_in[10];
    const float* We1   = (const float*)d_in[11];
    const float* be1   = (const float*)d_in[12];
    const float* W1_1  = (const float*)d_in[13];
    const float* b1_1  = (const float*)d_in[14];
    const float* g1    = (const float*)d_in[15];
    const float* bb1   = (const float*)d_in[16];
    const float* W2_1  = (const float*)d_in[17];
    const float* b2_1  = (const float*)d_in[18];
    float* out = (float*)d_out;

    const int N = in_sizes[0] / 128;   // 50000
    const int E = in_sizes[2] / 64;    // 800000

    char* ws = (char*)d_ws;
    size_t o = 0;
    auto alloc = [&](size_t bytes) { char* p = ws + o; o = (o + bytes + 255) & ~(size_t)255; return p; };
    unsigned short* pbuf = (unsigned short*)alloc((size_t)E * 64 * 2);
    float* tbuf   = (float*)alloc((size_t)N * 64 * 4);
    float* y0     = (float*)alloc((size_t)N * 64 * 4);
    short* WeB0   = (short*)alloc(128 * 64 * 2);
    short* W1B0   = (short*)alloc(64 * 128 * 2);
    short* WeB1   = (short*)alloc(64 * 64 * 2);
    float* stats  = (float*)alloc(512 * 4);
    int*   cnt    = (int*)alloc((size_t)N * 4);
    int*   offs   = (int*)alloc((size_t)(N + 1) * 4);
    int*   inv    = (int*)alloc((size_t)E * 4);
    float* sum0  = stats;
    float* scsh0 = stats + 128;
    float* sum1  = stats + 256;
    float* scsh1 = stats + 384;

    hipMemsetAsync(stats, 0, 512 * 4, stream);
    hipMemsetAsync(cnt, 0, (size_t)N * 4, stream);
    prep_kernel<<<64, 256, 0, stream>>>(We0, W1_0, We1, WeB0, W1B0, WeB1);

    const int eb256 = (E + 255) / 256;

    // ----- CSR by dst (offs) + edge -> sorted-position map (inv) -----
    hist_kernel<<<eb256, 256, 0, stream>>>(ei, cnt, E);
    scan_kernel<<<1, 1024, 0, stream>>>(cnt, offs, cnt, N);
    scatter_kernel<<<eb256, 256, 0, stream>>>(ei, cnt, inv, E);

    const int NT = (E + 15) / 16;
    const int EG2 = 768;   // edge2 grid (persistent, ~3 blocks/CU)
    const int EG1 = 1024;  // edge1 grid (persistent, ~4 blocks/CU)
    const int n4_blocks = (N + 3) / 4;

    // ----- layer 0 -----
    edge2_kernel<128><<<EG2, 256, 0, stream>>>(
        x, ei, eattr, WeB0, be0, W1B0, inv, pbuf, E, NT, EG2 * 4);
    gather_kernel<128><<<n4_blocks, 256, 0, stream>>>(
        pbuf, offs, x, W1_0, b1_0, tbuf, N);
    bnstats_kernel<<<256, 256, 0, stream>>>(tbuf, sum0, N * 64);
    bnfinal_kernel<<<1, 64, 0, stream>>>(sum0, g0, bb0, scsh0, 1.0f / N);
    mlp2_kernel<<<n4_blocks, 256, 0, stream>>>(tbuf, scsh0, W2_0, b2_0, y0, N, 1);

    // ----- layer 1 -----
    edge1_kernel<<<EG1, 256, 0, stream>>>(
        y0, ei, eattr, WeB1, be1, inv, pbuf, E, NT, EG1 * 4);
    gather1_kernel<<<n4_blocks, 256, 0, stream>>>(
        pbuf, offs, y0, W1_1, b1_1, tbuf, N);
    bnstats_kernel<<<256, 256, 0, stream>>>(tbuf, sum1, N * 64);
    bnfinal_kernel<<<1, 64, 0, stream>>>(sum1, g1, bb1, scsh1, 1.0f / N);
    mlp2_kernel<<<n4_blocks, 256, 0, stream>>>(tbuf, scsh1, W2_1, b2_1, out, N, 0);
}

// Round 7
// 1060.033 us; speedup vs baseline: 1.1902x; 1.1902x over previous
//
#include <hip/hip_runtime.h>
#include <hip/hip_bf16.h>

// ---------------------------------------------------------------------------
// GINE 2-layer GNN, MI355X (gfx950)  — round 7
//   t[n] = sum_{e: dst=n} relu(x[src]+ea_e)@W1^T  +  (x@W1^T + b1)
// Changes vs R6 (which spilled ~1GB scratch from A/B prefetch state):
//  - REVERT to R5 one-tile-per-wave edge kernels (no persistence, no A/B).
//  - x pre-cast to bf16 (xb, 12.8MB L3-resident; y0 emitted bf16 by mlp2).
//  - x-gather: 4x16B short8 loads issued UP-FRONT (sched_barrier pinned),
//    consumed at the A2 phase post-transpose (contiguous slices).
//  - LDS holds (ea+be) pre-relu; relu applied after x-add.
// ---------------------------------------------------------------------------

typedef short short8 __attribute__((ext_vector_type(8)));
typedef float f32x4 __attribute__((ext_vector_type(4)));

__device__ __forceinline__ short f2bf(float x) {
    unsigned u = __float_as_uint(x);
    unsigned r = (u + 0x7fffu + ((u >> 16) & 1u)) >> 16;   // RTNE
    return (short)r;
}
__device__ __forceinline__ float bf2f(unsigned short u) {
    return __uint_as_float(((unsigned)u) << 16);
}

// ---------------------------------------------------------------------------
// Counting sort of edges by dst -> inv (edge id -> sorted pos), offs (CSR)
// ---------------------------------------------------------------------------
__global__ __launch_bounds__(256) void hist_kernel(
    const int* __restrict__ ei, int* __restrict__ cnt, int E)
{
    int e = blockIdx.x * 256 + threadIdx.x;
    if (e < E) atomicAdd(&cnt[ei[E + e]], 1);
}

__global__ __launch_bounds__(1024) void scan_kernel(
    const int* __restrict__ cnt, int* __restrict__ offs,
    int* __restrict__ cursor, int N)
{
    __shared__ int wsum[16];
    __shared__ int chunk_base;
    int tid = threadIdx.x;
    int lane = tid & 63, wid = tid >> 6;
    if (tid == 0) chunk_base = 0;
    __syncthreads();
    for (int start = 0; start < N; start += 1024) {
        int i = start + tid;
        int v = (i < N) ? cnt[i] : 0;
        int s = v;
#pragma unroll
        for (int d = 1; d < 64; d <<= 1) {
            int t = __shfl_up(s, d);
            if (lane >= d) s += t;
        }
        if (lane == 63) wsum[wid] = s;
        __syncthreads();
        int wbase = 0;
        for (int w = 0; w < wid; ++w) wbase += wsum[w];
        int excl = chunk_base + wbase + s - v;
        if (i < N) { offs[i] = excl; cursor[i] = excl; }
        int tot = 0;
        for (int w = 0; w < 16; ++w) tot += wsum[w];
        __syncthreads();
        if (tid == 0) chunk_base += tot;
        __syncthreads();
    }
    if (threadIdx.x == 0) offs[N] = chunk_base;
}

__global__ __launch_bounds__(256) void scatter_kernel(
    const int* __restrict__ ei, int* __restrict__ cursor,
    int* __restrict__ inv, int E)
{
    int e = blockIdx.x * 256 + threadIdx.x;
    if (e >= E) return;
    int d = ei[E + e];
    int pos = atomicAdd(&cursor[d], 1);
    inv[e] = pos;
}

// ---------------------------------------------------------------------------
// x -> bf16 cast (grid-stride)
// ---------------------------------------------------------------------------
__global__ __launch_bounds__(256) void xcast_kernel(
    const float* __restrict__ x, unsigned short* __restrict__ xb, int total)
{
    for (int i = blockIdx.x * 256 + threadIdx.x; i < total; i += gridDim.x * 256)
        xb[i] = (unsigned short)f2bf(x[i]);
}

// ---------------------------------------------------------------------------
// L0 edge kernel (DIN=128): wave = 16 edges, one tile per wave.
// Load burst {ei, inv, eattr, xb} -> GEMM1 -> LDS (ea+be) -> A2 = relu(LDS+x)
// -> GEMM2 (p = m @ W1^T) -> store bf16 at dst-sorted row.
// ---------------------------------------------------------------------------
template<int DIN>
__global__ __launch_bounds__(256) void edge2_kernel(
    const unsigned short* __restrict__ xb,   // [N][DIN] bf16
    const int*    __restrict__ ei,           // [2][E] (src used)
    const float*  __restrict__ eattr,        // [E][64]
    const short*  __restrict__ WeB,          // [DIN][64] bf16
    const float*  __restrict__ be,           // [DIN]
    const short*  __restrict__ W1B,          // [64][DIN] bf16
    const int*    __restrict__ inv,          // [E] edge -> sorted pos
    unsigned short* __restrict__ pbuf,       // [E][64] bf16 (sorted rows)
    int E)
{
    constexpr int S = DIN + 8;
    constexpr int KK = DIN / 32;
    __shared__ short lds[4][16][S];
    const int wave = threadIdx.x >> 6;
    const int lane = threadIdx.x & 63;
    const int ebase = (blockIdx.x * 4 + wave) * 16;
    if (ebase >= E) return;
    const int g = lane >> 4, c = lane & 15;
    short* myl = &lds[wave][0][0];

    // ---- load burst ----
    int ce = ebase + c; if (ce >= E) ce = E - 1;
    int se_c = ei[ce];

    int sp[4];
#pragma unroll
    for (int r = 0; r < 4; ++r) {
        int e = ebase + g * 4 + r;
        sp[r] = (e < E) ? inv[e] : -1;
    }

    const float* ar = eattr + (size_t)ce * 64 + g * 8;
    f32x4 a0 = *(const f32x4*)(ar);
    f32x4 a1 = *(const f32x4*)(ar + 4);
    f32x4 a2v = *(const f32x4*)(ar + 32);
    f32x4 a3 = *(const f32x4*)(ar + 36);

    // x slices for the A2 phase (bf16, contiguous): issued NOW, used later
    short8 xv[KK];
    const unsigned short* xr = xb + (size_t)se_c * DIN + g * 8;
#pragma unroll
    for (int kk = 0; kk < KK; ++kk)
        xv[kk] = *(const short8*)(xr + kk * 32);
    __builtin_amdgcn_sched_barrier(0);   // pin: loads stay issued up here

    // ---- GEMM1 -> LDS (ea + be, pre-relu) ----
    short8 afr0, afr1;
    afr0[0]=f2bf(a0[0]); afr0[1]=f2bf(a0[1]); afr0[2]=f2bf(a0[2]); afr0[3]=f2bf(a0[3]);
    afr0[4]=f2bf(a1[0]); afr0[5]=f2bf(a1[1]); afr0[6]=f2bf(a1[2]); afr0[7]=f2bf(a1[3]);
    afr1[0]=f2bf(a2v[0]); afr1[1]=f2bf(a2v[1]); afr1[2]=f2bf(a2v[2]); afr1[3]=f2bf(a2v[3]);
    afr1[4]=f2bf(a3[0]); afr1[5]=f2bf(a3[1]); afr1[6]=f2bf(a3[2]); afr1[7]=f2bf(a3[3]);

#pragma unroll
    for (int fc = 0; fc < DIN / 16; ++fc) {
        const short* brow = WeB + (size_t)(fc * 16 + c) * 64 + g * 8;
        short8 b0 = *(const short8*)(brow);
        short8 b1 = *(const short8*)(brow + 32);
        f32x4 acc = {0.f, 0.f, 0.f, 0.f};
        acc = __builtin_amdgcn_mfma_f32_16x16x32_bf16(afr0, b0, acc, 0, 0, 0);
        acc = __builtin_amdgcn_mfma_f32_16x16x32_bf16(afr1, b1, acc, 0, 0, 0);
        const int f = fc * 16 + c;
        const float bev = be[f];
#pragma unroll
        for (int r = 0; r < 4; ++r)
            myl[(g * 4 + r) * S + f] = f2bf(acc[r] + bev);
    }

    asm volatile("s_waitcnt lgkmcnt(0)" ::: "memory");
    __builtin_amdgcn_sched_barrier(0);

    // ---- A2: m = relu(ea + x[src]) per lane's own edge column ----
    short8 a2[KK];
#pragma unroll
    for (int kk = 0; kk < KK; ++kk) {
        short8 v = *(const short8*)(myl + c * S + kk * 32 + g * 8);
#pragma unroll
        for (int j = 0; j < 8; ++j) {
            float f = bf2f((unsigned short)v[j]) + bf2f((unsigned short)xv[kk][j]);
            a2[kk][j] = f2bf(fmaxf(f, 0.f));
        }
    }

    // ---- GEMM2: p = m @ W1^T ; store bf16 at sorted row ----
#pragma unroll
    for (int cc = 0; cc < 4; ++cc) {
        f32x4 acc2 = {0.f, 0.f, 0.f, 0.f};
#pragma unroll
        for (int kk = 0; kk < KK; ++kk) {
            short8 b0 = *(const short8*)(W1B + (size_t)(cc * 16 + c) * DIN + kk * 32 + g * 8);
            acc2 = __builtin_amdgcn_mfma_f32_16x16x32_bf16(a2[kk], b0, acc2, 0, 0, 0);
        }
#pragma unroll
        for (int r = 0; r < 4; ++r)
            if (sp[r] >= 0)
                pbuf[(size_t)sp[r] * 64 + cc * 16 + c] = (unsigned short)f2bf(acc2[r]);
    }
}

// ---------------------------------------------------------------------------
// L1 edge kernel (DIN=64, no GEMM2): m = relu(y0[src] + ea + be) stored
// bf16 at sorted row; lane (g,c) owns edge c's slices {g*8, 32+g*8}.
// ---------------------------------------------------------------------------
__global__ __launch_bounds__(256) void edge1_kernel(
    const unsigned short* __restrict__ yb,   // [N][64] bf16 (relu'd y0)
    const int*    __restrict__ ei,
    const float*  __restrict__ eattr,
    const short*  __restrict__ WeB,          // [64][64] bf16
    const float*  __restrict__ be,
    const int*    __restrict__ inv,
    unsigned short* __restrict__ pbuf,       // [E][64] bf16 m (sorted rows)
    int E)
{
    constexpr int S = 72;
    __shared__ short lds[4][16][S];
    const int wave = threadIdx.x >> 6;
    const int lane = threadIdx.x & 63;
    const int ebase = (blockIdx.x * 4 + wave) * 16;
    if (ebase >= E) return;
    const int g = lane >> 4, c = lane & 15;
    short* myl = &lds[wave][0][0];

    // ---- load burst ----
    int ce = ebase + c;
    bool cv = ce < E;
    if (!cv) ce = E - 1;
    int se_c = ei[ce];
    int sp_c = cv ? inv[ce] : -1;

    const float* ar = eattr + (size_t)ce * 64 + g * 8;
    f32x4 a0 = *(const f32x4*)(ar);
    f32x4 a1 = *(const f32x4*)(ar + 4);
    f32x4 a2v = *(const f32x4*)(ar + 32);
    f32x4 a3 = *(const f32x4*)(ar + 36);

    short8 xv0, xv1;
    {
        const unsigned short* xr = yb + (size_t)se_c * 64 + g * 8;
        xv0 = *(const short8*)(xr);
        xv1 = *(const short8*)(xr + 32);
    }
    __builtin_amdgcn_sched_barrier(0);

    // ---- GEMM1 -> LDS (ea + be, pre-relu) ----
    short8 afr0, afr1;
    afr0[0]=f2bf(a0[0]); afr0[1]=f2bf(a0[1]); afr0[2]=f2bf(a0[2]); afr0[3]=f2bf(a0[3]);
    afr0[4]=f2bf(a1[0]); afr0[5]=f2bf(a1[1]); afr0[6]=f2bf(a1[2]); afr0[7]=f2bf(a1[3]);
    afr1[0]=f2bf(a2v[0]); afr1[1]=f2bf(a2v[1]); afr1[2]=f2bf(a2v[2]); afr1[3]=f2bf(a2v[3]);
    afr1[4]=f2bf(a3[0]); afr1[5]=f2bf(a3[1]); afr1[6]=f2bf(a3[2]); afr1[7]=f2bf(a3[3]);

#pragma unroll
    for (int fc = 0; fc < 4; ++fc) {
        const short* brow = WeB + (size_t)(fc * 16 + c) * 64 + g * 8;
        short8 b0 = *(const short8*)(brow);
        short8 b1 = *(const short8*)(brow + 32);
        f32x4 acc = {0.f, 0.f, 0.f, 0.f};
        acc = __builtin_amdgcn_mfma_f32_16x16x32_bf16(afr0, b0, acc, 0, 0, 0);
        acc = __builtin_amdgcn_mfma_f32_16x16x32_bf16(afr1, b1, acc, 0, 0, 0);
        const int f = fc * 16 + c;
        const float bev = be[f];
#pragma unroll
        for (int r = 0; r < 4; ++r)
            myl[(g * 4 + r) * S + f] = f2bf(acc[r] + bev);
    }

    asm volatile("s_waitcnt lgkmcnt(0)" ::: "memory");
    __builtin_amdgcn_sched_barrier(0);

    // ---- m = relu(ea + y0[src]) ; store lane-owned row slices ----
    short8 v0 = *(const short8*)(myl + c * S + g * 8);
    short8 v1 = *(const short8*)(myl + c * S + 32 + g * 8);
    short8 out0, out1;
#pragma unroll
    for (int j = 0; j < 8; ++j) {
        float f0 = bf2f((unsigned short)v0[j]) + bf2f((unsigned short)xv0[j]);
        out0[j] = f2bf(fmaxf(f0, 0.f));
        float f1 = bf2f((unsigned short)v1[j]) + bf2f((unsigned short)xv1[j]);
        out1[j] = f2bf(fmaxf(f1, 0.f));
    }
    if (sp_c >= 0) {
        *(short8*)(pbuf + (size_t)sp_c * 64 + g * 8) = out0;
        *(short8*)(pbuf + (size_t)sp_c * 64 + 32 + g * 8) = out1;
    }
}

// ---------------------------------------------------------------------------
// L0 gather (fused dense xw1): wave per node, lane = out feature f.
// ---------------------------------------------------------------------------
template<int DIN>
__global__ __launch_bounds__(256) void gather_kernel(
    const unsigned short* __restrict__ pbuf,
    const int* __restrict__ offs,
    const float* __restrict__ x, const float* __restrict__ W1,
    const float* __restrict__ b1, float* __restrict__ t, int N)
{
    int wid = threadIdx.x >> 6, lane = threadIdx.x & 63;
    int n = blockIdx.x * 4 + wid;
    if (n >= N) return;

    const f32x4* xr = (const f32x4*)(x + (size_t)n * DIN);
    const f32x4* wr = (const f32x4*)(W1 + (size_t)lane * DIN);
    float acc = b1[lane];
#pragma unroll
    for (int k = 0; k < DIN / 4; ++k) {
        f32x4 xx = xr[k], w = wr[k];
        acc += xx[0] * w[0] + xx[1] * w[1] + xx[2] * w[2] + xx[3] * w[3];
    }

    int i0 = offs[n], i1 = offs[n + 1];
    const unsigned short* p = pbuf + (size_t)i0 * 64 + lane;
    int cnt = i1 - i0;
    int i = 0;
    for (; i + 3 < cnt; i += 4) {
        acc += bf2f(p[0]) + bf2f(p[64]) + bf2f(p[128]) + bf2f(p[192]);
        p += 256;
    }
    for (; i < cnt; ++i) { acc += bf2f(p[0]); p += 64; }
    t[(size_t)n * 64 + lane] = acc;
}

// ---------------------------------------------------------------------------
// L1 gather + node-level W1 apply (f32 exact)
// ---------------------------------------------------------------------------
__global__ __launch_bounds__(256) void gather1_kernel(
    const unsigned short* __restrict__ pbuf,
    const int* __restrict__ offs,
    const float* __restrict__ y0, const float* __restrict__ W1,
    const float* __restrict__ b1, float* __restrict__ t, int N)
{
    __shared__ __align__(16) float sm[4][64];
    int wid = threadIdx.x >> 6, lane = threadIdx.x & 63;
    int n = blockIdx.x * 4 + wid;
    if (n >= N) return;

    int i0 = offs[n], i1 = offs[n + 1];
    float s = y0[(size_t)n * 64 + lane];
    const unsigned short* p = pbuf + (size_t)i0 * 64 + lane;
    int cnt = i1 - i0;
    int i = 0;
    for (; i + 3 < cnt; i += 4) {
        s += bf2f(p[0]) + bf2f(p[64]) + bf2f(p[128]) + bf2f(p[192]);
        p += 256;
    }
    for (; i < cnt; ++i) { s += bf2f(p[0]); p += 64; }
    sm[wid][lane] = s;

    asm volatile("s_waitcnt lgkmcnt(0)" ::: "memory");
    __builtin_amdgcn_sched_barrier(0);

    const f32x4* wr = (const f32x4*)(W1 + (size_t)lane * 64);
    const f32x4* sr = (const f32x4*)(sm[wid]);
    float acc = b1[lane];
#pragma unroll
    for (int kk = 0; kk < 16; ++kk) {
        f32x4 w = wr[kk], ss = sr[kk];
        acc += ss[0] * w[0] + ss[1] * w[1] + ss[2] * w[2] + ss[3] * w[3];
    }
    t[(size_t)n * 64 + lane] = acc;
}

// ---------------------------------------------------------------------------
// BN stats + final
// ---------------------------------------------------------------------------
__global__ __launch_bounds__(256) void bnstats_kernel(
    const float* __restrict__ t, float* __restrict__ sums, int total)
{
    int tid = threadIdx.x;
    float s = 0.f, s2 = 0.f;
    for (int i = blockIdx.x * 256 + tid; i < total; i += gridDim.x * 256) {
        float v = t[i];
        s += v; s2 += v * v;
    }
    __shared__ float ls[256], ls2[256];
    ls[tid] = s; ls2[tid] = s2;
    __syncthreads();
    if (tid < 64) {
        s  = ls[tid]  + ls[tid + 64]  + ls[tid + 128]  + ls[tid + 192];
        s2 = ls2[tid] + ls2[tid + 64] + ls2[tid + 128] + ls2[tid + 192];
        atomicAdd(&sums[tid], s);
        atomicAdd(&sums[64 + tid], s2);
    }
}

__global__ void bnfinal_kernel(const float* __restrict__ sums,
                               const float* __restrict__ g,
                               const float* __restrict__ bb,
                               float* __restrict__ scsh, float invN)
{
    int f = threadIdx.x;  // 64 threads
    float mean = sums[f] * invN;
    float var  = sums[64 + f] * invN - mean * mean;
    float sc = g[f] * rsqrtf(var + 1e-5f);
    scsh[f] = sc;
    scsh[64 + f] = bb[f] - mean * sc;
}

// ---------------------------------------------------------------------------
// mlp2: h = relu(t*scale+shift); out = h @ W2^T + b2.
// relu_out=1: also emit bf16 copy (yb) for the L1 edge kernel.
// ---------------------------------------------------------------------------
__global__ __launch_bounds__(256) void mlp2_kernel(
    const float* __restrict__ t, const float* __restrict__ scsh,
    const float* __restrict__ W2, const float* __restrict__ b2,
    float* __restrict__ out, unsigned short* __restrict__ outb,
    int N, int relu_out)
{
    __shared__ __align__(16) float hs[4][64];
    int tid = threadIdx.x;
    int nl = tid >> 6, k = tid & 63;
    int n = blockIdx.x * 4 + nl;
    float h = 0.f;
    if (n < N) h = fmaxf(t[(size_t)n * 64 + k] * scsh[k] + scsh[64 + k], 0.f);
    hs[nl][k] = h;
    __syncthreads();
    if (n >= N) return;
    const int f = k;
    const f32x4* wr = (const f32x4*)(W2 + (size_t)f * 64);
    const f32x4* hr = (const f32x4*)(hs[nl]);
    float acc = b2[f];
#pragma unroll
    for (int kk = 0; kk < 16; ++kk) {
        f32x4 w = wr[kk], hh = hr[kk];
        acc += hh[0] * w[0] + hh[1] * w[1] + hh[2] * w[2] + hh[3] * w[3];
    }
    if (relu_out) {
        acc = fmaxf(acc, 0.f);
        outb[(size_t)n * 64 + f] = (unsigned short)f2bf(acc);
    }
    out[(size_t)n * 64 + f] = acc;
}

// ---------------------------------------------------------------------------
// Weight prep: f32 -> bf16
// ---------------------------------------------------------------------------
__global__ __launch_bounds__(256) void prep_kernel(
    const float* __restrict__ We0, const float* __restrict__ W1_0,
    const float* __restrict__ We1,
    short* __restrict__ WeB0, short* __restrict__ W1B0,
    short* __restrict__ WeB1)
{
    int i = blockIdx.x * 256 + threadIdx.x;
    if (i < 128 * 64) WeB0[i] = f2bf(We0[i]);
    if (i < 64 * 128) W1B0[i] = f2bf(W1_0[i]);
    if (i < 64 * 64)  WeB1[i] = f2bf(We1[i]);
}

extern "C" void kernel_launch(void* const* d_in, const int* in_sizes, int n_in,
                              void* d_out, int out_size, void* d_ws, size_t ws_size,
                              hipStream_t stream)
{
    (void)n_in; (void)out_size; (void)ws_size;
    const float* x     = (const float*)d_in[0];
    const int*   ei    = (const int*)d_in[1];
    const float* eattr = (const float*)d_in[2];
    const float* We0   = (const float*)d_in[3];
    const float* be0   = (const float*)d_in[4];
    const float* W1_0  = (const float*)d_in[5];
    const float* b1_0  = (const float*)d_in[6];
    const float* g0    = (const float*)d_in[7];
    const float* bb0   = (const float*)d_in[8];
    const float* W2_0  = (const float*)d_in[9];
    const float* b2_0  = (const float*)d_in[10];
    const float* We1   = (const float*)d_in[11];
    const float* be1   = (const float*)d_in[12];
    const float* W1_1  = (const float*)d_in[13];
    const float* b1_1  = (const float*)d_in[14];
    const float* g1    = (const float*)d_in[15];
    const float* bb1   = (const float*)d_in[16];
    const float* W2_1  = (const float*)d_in[17];
    const float* b2_1  = (const float*)d_in[18];
    float* out = (float*)d_out;

    const int N = in_sizes[0] / 128;   // 50000
    const int E = in_sizes[2] / 64;    // 800000

    char* ws = (char*)d_ws;
    size_t o = 0;
    auto alloc = [&](size_t bytes) { char* p = ws + o; o = (o + bytes + 255) & ~(size_t)255; return p; };
    unsigned short* pbuf = (unsigned short*)alloc((size_t)E * 64 * 2);
    float* tbuf   = (float*)alloc((size_t)N * 64 * 4);
    float* y0     = (float*)alloc((size_t)N * 64 * 4);
    unsigned short* xb = (unsigned short*)alloc((size_t)N * 128 * 2);
    unsigned short* yb = (unsigned short*)alloc((size_t)N * 64 * 2);
    short* WeB0   = (short*)alloc(128 * 64 * 2);
    short* W1B0   = (short*)alloc(64 * 128 * 2);
    short* WeB1   = (short*)alloc(64 * 64 * 2);
    float* stats  = (float*)alloc(512 * 4);
    int*   cnt    = (int*)alloc((size_t)N * 4);
    int*   offs   = (int*)alloc((size_t)(N + 1) * 4);
    int*   inv    = (int*)alloc((size_t)E * 4);
    float* sum0  = stats;
    float* scsh0 = stats + 128;
    float* sum1  = stats + 256;
    float* scsh1 = stats + 384;

    hipMemsetAsync(stats, 0, 512 * 4, stream);
    hipMemsetAsync(cnt, 0, (size_t)N * 4, stream);
    prep_kernel<<<64, 256, 0, stream>>>(We0, W1_0, We1, WeB0, W1B0, WeB1);
    xcast_kernel<<<2048, 256, 0, stream>>>(x, xb, N * 128);

    const int eb256 = (E + 255) / 256;

    // ----- CSR by dst (offs) + edge -> sorted-position map (inv) -----
    hist_kernel<<<eb256, 256, 0, stream>>>(ei, cnt, E);
    scan_kernel<<<1, 1024, 0, stream>>>(cnt, offs, cnt, N);
    scatter_kernel<<<eb256, 256, 0, stream>>>(ei, cnt, inv, E);

    const int edge_blocks = (E + 63) / 64;
    const int n4_blocks   = (N + 3) / 4;

    // ----- layer 0 -----
    edge2_kernel<128><<<edge_blocks, 256, 0, stream>>>(
        xb, ei, eattr, WeB0, be0, W1B0, inv, pbuf, E);
    gather_kernel<128><<<n4_blocks, 256, 0, stream>>>(
        pbuf, offs, x, W1_0, b1_0, tbuf, N);
    bnstats_kernel<<<256, 256, 0, stream>>>(tbuf, sum0, N * 64);
    bnfinal_kernel<<<1, 64, 0, stream>>>(sum0, g0, bb0, scsh0, 1.0f / N);
    mlp2_kernel<<<n4_blocks, 256, 0, stream>>>(tbuf, scsh0, W2_0, b2_0, y0, yb, N, 1);

    // ----- layer 1 -----
    edge1_kernel<<<edge_blocks, 256, 0, stream>>>(
        yb, ei, eattr, WeB1, be1, inv, pbuf, E);
    gather1_kernel<<<n4_blocks, 256, 0, stream>>>(
        pbuf, offs, y0, W1_1, b1_1, tbuf, N);
    bnstats_kernel<<<256, 256, 0, stream>>>(tbuf, sum1, N * 64);
    bnfinal_kernel<<<1, 64, 0, stream>>>(sum1, g1, bb1, scsh1, 1.0f / N);
    mlp2_kernel<<<n4_blocks, 256, 0, stream>>>(tbuf, scsh1, W2_1, b2_1, out, yb, N, 0);
}

// Round 8
// 615.345 us; speedup vs baseline: 2.0503x; 1.7227x over previous
//
#include <hip/hip_runtime.h>
#include <hip/hip_bf16.h>

// ---------------------------------------------------------------------------
// GINE 2-layer GNN, MI355X (gfx950)  — round 8
// R7 post-mortem: per-lane dense dot products (gather's fused x@W1^T,
// gather1's W1 apply, mlp2's W2 apply) are instruction/latency-bound:
// lane-strided weight rows = 64-way uncoalesced VMEM per instruction.
// Fix: ALL dense node-level GEMMs go through a node-tile MFMA kernel
// (16 nodes x 64 feats per wave, edge-kernel fragment layout); gathers
// become pure streaming over contiguous sorted pbuf rows.
//   L0: ngemm<128> (xw1=xb@W1B0^T+b1) -> gather0 (t = xw1 + sum pbuf)
//   L1: gathersum1 (s = y0 + sum pbuf, bf16) -> ngemm<64> (t = s@W1B1^T+b1)
//   mlp2 -> ngemm_bn (A = bf16(relu(t*sc+sh)) inline, W2 bf16 MFMA)
// ---------------------------------------------------------------------------

typedef short short8 __attribute__((ext_vector_type(8)));
typedef float f32x4 __attribute__((ext_vector_type(4)));

__device__ __forceinline__ short f2bf(float x) {
    unsigned u = __float_as_uint(x);
    unsigned r = (u + 0x7fffu + ((u >> 16) & 1u)) >> 16;   // RTNE
    return (short)r;
}
__device__ __forceinline__ float bf2f(unsigned short u) {
    return __uint_as_float(((unsigned)u) << 16);
}

// ---------------------------------------------------------------------------
// Counting sort of edges by dst -> inv (edge id -> sorted pos), offs (CSR)
// ---------------------------------------------------------------------------
__global__ __launch_bounds__(256) void hist_kernel(
    const int* __restrict__ ei, int* __restrict__ cnt, int E)
{
    int e = blockIdx.x * 256 + threadIdx.x;
    if (e < E) atomicAdd(&cnt[ei[E + e]], 1);
}

__global__ __launch_bounds__(1024) void scan_kernel(
    const int* __restrict__ cnt, int* __restrict__ offs,
    int* __restrict__ cursor, int N)
{
    __shared__ int wsum[16];
    __shared__ int chunk_base;
    int tid = threadIdx.x;
    int lane = tid & 63, wid = tid >> 6;
    if (tid == 0) chunk_base = 0;
    __syncthreads();
    for (int start = 0; start < N; start += 1024) {
        int i = start + tid;
        int v = (i < N) ? cnt[i] : 0;
        int s = v;
#pragma unroll
        for (int d = 1; d < 64; d <<= 1) {
            int t = __shfl_up(s, d);
            if (lane >= d) s += t;
        }
        if (lane == 63) wsum[wid] = s;
        __syncthreads();
        int wbase = 0;
        for (int w = 0; w < wid; ++w) wbase += wsum[w];
        int excl = chunk_base + wbase + s - v;
        if (i < N) { offs[i] = excl; cursor[i] = excl; }
        int tot = 0;
        for (int w = 0; w < 16; ++w) tot += wsum[w];
        __syncthreads();
        if (tid == 0) chunk_base += tot;
        __syncthreads();
    }
    if (threadIdx.x == 0) offs[N] = chunk_base;
}

__global__ __launch_bounds__(256) void scatter_kernel(
    const int* __restrict__ ei, int* __restrict__ cursor,
    int* __restrict__ inv, int E)
{
    int e = blockIdx.x * 256 + threadIdx.x;
    if (e >= E) return;
    int d = ei[E + e];
    int pos = atomicAdd(&cursor[d], 1);
    inv[e] = pos;
}

// ---------------------------------------------------------------------------
// x -> bf16 cast (grid-stride)
// ---------------------------------------------------------------------------
__global__ __launch_bounds__(256) void xcast_kernel(
    const float* __restrict__ x, unsigned short* __restrict__ xb, int total)
{
    for (int i = blockIdx.x * 256 + threadIdx.x; i < total; i += gridDim.x * 256)
        xb[i] = (unsigned short)f2bf(x[i]);
}

// ---------------------------------------------------------------------------
// L0 edge kernel (DIN=128): wave = 16 edges, one tile per wave.
// ---------------------------------------------------------------------------
template<int DIN>
__global__ __launch_bounds__(256) void edge2_kernel(
    const unsigned short* __restrict__ xb,   // [N][DIN] bf16
    const int*    __restrict__ ei,           // [2][E] (src used)
    const float*  __restrict__ eattr,        // [E][64]
    const short*  __restrict__ WeB,          // [DIN][64] bf16
    const float*  __restrict__ be,           // [DIN]
    const short*  __restrict__ W1B,          // [64][DIN] bf16
    const int*    __restrict__ inv,          // [E] edge -> sorted pos
    unsigned short* __restrict__ pbuf,       // [E][64] bf16 (sorted rows)
    int E)
{
    constexpr int S = DIN + 8;
    constexpr int KK = DIN / 32;
    __shared__ short lds[4][16][S];
    const int wave = threadIdx.x >> 6;
    const int lane = threadIdx.x & 63;
    const int ebase = (blockIdx.x * 4 + wave) * 16;
    if (ebase >= E) return;
    const int g = lane >> 4, c = lane & 15;
    short* myl = &lds[wave][0][0];

    // ---- load burst ----
    int ce = ebase + c; if (ce >= E) ce = E - 1;
    int se_c = ei[ce];

    int sp[4];
#pragma unroll
    for (int r = 0; r < 4; ++r) {
        int e = ebase + g * 4 + r;
        sp[r] = (e < E) ? inv[e] : -1;
    }

    const float* ar = eattr + (size_t)ce * 64 + g * 8;
    f32x4 a0 = *(const f32x4*)(ar);
    f32x4 a1 = *(const f32x4*)(ar + 4);
    f32x4 a2v = *(const f32x4*)(ar + 32);
    f32x4 a3 = *(const f32x4*)(ar + 36);

    // x slices for the A2 phase (bf16, contiguous): issued NOW, used later
    short8 xv[KK];
    const unsigned short* xr = xb + (size_t)se_c * DIN + g * 8;
#pragma unroll
    for (int kk = 0; kk < KK; ++kk)
        xv[kk] = *(const short8*)(xr + kk * 32);
    __builtin_amdgcn_sched_barrier(0);   // pin: loads stay issued up here

    // ---- GEMM1 -> LDS (ea + be, pre-relu) ----
    short8 afr0, afr1;
    afr0[0]=f2bf(a0[0]); afr0[1]=f2bf(a0[1]); afr0[2]=f2bf(a0[2]); afr0[3]=f2bf(a0[3]);
    afr0[4]=f2bf(a1[0]); afr0[5]=f2bf(a1[1]); afr0[6]=f2bf(a1[2]); afr0[7]=f2bf(a1[3]);
    afr1[0]=f2bf(a2v[0]); afr1[1]=f2bf(a2v[1]); afr1[2]=f2bf(a2v[2]); afr1[3]=f2bf(a2v[3]);
    afr1[4]=f2bf(a3[0]); afr1[5]=f2bf(a3[1]); afr1[6]=f2bf(a3[2]); afr1[7]=f2bf(a3[3]);

#pragma unroll
    for (int fc = 0; fc < DIN / 16; ++fc) {
        const short* brow = WeB + (size_t)(fc * 16 + c) * 64 + g * 8;
        short8 b0 = *(const short8*)(brow);
        short8 b1 = *(const short8*)(brow + 32);
        f32x4 acc = {0.f, 0.f, 0.f, 0.f};
        acc = __builtin_amdgcn_mfma_f32_16x16x32_bf16(afr0, b0, acc, 0, 0, 0);
        acc = __builtin_amdgcn_mfma_f32_16x16x32_bf16(afr1, b1, acc, 0, 0, 0);
        const int f = fc * 16 + c;
        const float bev = be[f];
#pragma unroll
        for (int r = 0; r < 4; ++r)
            myl[(g * 4 + r) * S + f] = f2bf(acc[r] + bev);
    }

    asm volatile("s_waitcnt lgkmcnt(0)" ::: "memory");
    __builtin_amdgcn_sched_barrier(0);

    // ---- A2: m = relu(ea + x[src]) per lane's own edge column ----
    short8 a2[KK];
#pragma unroll
    for (int kk = 0; kk < KK; ++kk) {
        short8 v = *(const short8*)(myl + c * S + kk * 32 + g * 8);
#pragma unroll
        for (int j = 0; j < 8; ++j) {
            float f = bf2f((unsigned short)v[j]) + bf2f((unsigned short)xv[kk][j]);
            a2[kk][j] = f2bf(fmaxf(f, 0.f));
        }
    }

    // ---- GEMM2: p = m @ W1^T ; store bf16 at sorted row ----
#pragma unroll
    for (int cc = 0; cc < 4; ++cc) {
        f32x4 acc2 = {0.f, 0.f, 0.f, 0.f};
#pragma unroll
        for (int kk = 0; kk < KK; ++kk) {
            short8 b0 = *(const short8*)(W1B + (size_t)(cc * 16 + c) * DIN + kk * 32 + g * 8);
            acc2 = __builtin_amdgcn_mfma_f32_16x16x32_bf16(a2[kk], b0, acc2, 0, 0, 0);
        }
#pragma unroll
        for (int r = 0; r < 4; ++r)
            if (sp[r] >= 0)
                pbuf[(size_t)sp[r] * 64 + cc * 16 + c] = (unsigned short)f2bf(acc2[r]);
    }
}

// ---------------------------------------------------------------------------
// L1 edge kernel (DIN=64, no GEMM2): m = relu(y0[src] + ea + be) stored
// bf16 at sorted row; lane (g,c) owns edge c's slices {g*8, 32+g*8}.
// ---------------------------------------------------------------------------
__global__ __launch_bounds__(256) void edge1_kernel(
    const unsigned short* __restrict__ yb,   // [N][64] bf16 (relu'd y0)
    const int*    __restrict__ ei,
    const float*  __restrict__ eattr,
    const short*  __restrict__ WeB,          // [64][64] bf16
    const float*  __restrict__ be,
    const int*    __restrict__ inv,
    unsigned short* __restrict__ pbuf,       // [E][64] bf16 m (sorted rows)
    int E)
{
    constexpr int S = 72;
    __shared__ short lds[4][16][S];
    const int wave = threadIdx.x >> 6;
    const int lane = threadIdx.x & 63;
    const int ebase = (blockIdx.x * 4 + wave) * 16;
    if (ebase >= E) return;
    const int g = lane >> 4, c = lane & 15;
    short* myl = &lds[wave][0][0];

    // ---- load burst ----
    int ce = ebase + c;
    bool cv = ce < E;
    if (!cv) ce = E - 1;
    int se_c = ei[ce];
    int sp_c = cv ? inv[ce] : -1;

    const float* ar = eattr + (size_t)ce * 64 + g * 8;
    f32x4 a0 = *(const f32x4*)(ar);
    f32x4 a1 = *(const f32x4*)(ar + 4);
    f32x4 a2v = *(const f32x4*)(ar + 32);
    f32x4 a3 = *(const f32x4*)(ar + 36);

    short8 xv0, xv1;
    {
        const unsigned short* xr = yb + (size_t)se_c * 64 + g * 8;
        xv0 = *(const short8*)(xr);
        xv1 = *(const short8*)(xr + 32);
    }
    __builtin_amdgcn_sched_barrier(0);

    // ---- GEMM1 -> LDS (ea + be, pre-relu) ----
    short8 afr0, afr1;
    afr0[0]=f2bf(a0[0]); afr0[1]=f2bf(a0[1]); afr0[2]=f2bf(a0[2]); afr0[3]=f2bf(a0[3]);
    afr0[4]=f2bf(a1[0]); afr0[5]=f2bf(a1[1]); afr0[6]=f2bf(a1[2]); afr0[7]=f2bf(a1[3]);
    afr1[0]=f2bf(a2v[0]); afr1[1]=f2bf(a2v[1]); afr1[2]=f2bf(a2v[2]); afr1[3]=f2bf(a2v[3]);
    afr1[4]=f2bf(a3[0]); afr1[5]=f2bf(a3[1]); afr1[6]=f2bf(a3[2]); afr1[7]=f2bf(a3[3]);

#pragma unroll
    for (int fc = 0; fc < 4; ++fc) {
        const short* brow = WeB + (size_t)(fc * 16 + c) * 64 + g * 8;
        short8 b0 = *(const short8*)(brow);
        short8 b1 = *(const short8*)(brow + 32);
        f32x4 acc = {0.f, 0.f, 0.f, 0.f};
        acc = __builtin_amdgcn_mfma_f32_16x16x32_bf16(afr0, b0, acc, 0, 0, 0);
        acc = __builtin_amdgcn_mfma_f32_16x16x32_bf16(afr1, b1, acc, 0, 0, 0);
        const int f = fc * 16 + c;
        const float bev = be[f];
#pragma unroll
        for (int r = 0; r < 4; ++r)
            myl[(g * 4 + r) * S + f] = f2bf(acc[r] + bev);
    }

    asm volatile("s_waitcnt lgkmcnt(0)" ::: "memory");
    __builtin_amdgcn_sched_barrier(0);

    // ---- m = relu(ea + y0[src]) ; store lane-owned row slices ----
    short8 v0 = *(const short8*)(myl + c * S + g * 8);
    short8 v1 = *(const short8*)(myl + c * S + 32 + g * 8);
    short8 out0, out1;
#pragma unroll
    for (int j = 0; j < 8; ++j) {
        float f0 = bf2f((unsigned short)v0[j]) + bf2f((unsigned short)xv0[j]);
        out0[j] = f2bf(fmaxf(f0, 0.f));
        float f1 = bf2f((unsigned short)v1[j]) + bf2f((unsigned short)xv1[j]);
        out1[j] = f2bf(fmaxf(f1, 0.f));
    }
    if (sp_c >= 0) {
        *(short8*)(pbuf + (size_t)sp_c * 64 + g * 8) = out0;
        *(short8*)(pbuf + (size_t)sp_c * 64 + 32 + g * 8) = out1;
    }
}

// ---------------------------------------------------------------------------
// Node-tile MFMA GEMM: out[n][f] = b[f] + sum_k A[n][k] * W[f][k]
// A bf16 [N][DIN], W bf16 [64][DIN], out f32 [N][64].
// Wave = 16 nodes; A-frag lane (g,c): A[nbase+c][kt*32+g*8+j].
// ---------------------------------------------------------------------------
template<int DIN>
__global__ __launch_bounds__(256) void ngemm_kernel(
    const unsigned short* __restrict__ A,
    const short* __restrict__ W, const float* __restrict__ b,
    float* __restrict__ out, int N)
{
    constexpr int KK = DIN / 32;
    const int wave = threadIdx.x >> 6;
    const int lane = threadIdx.x & 63;
    const int nbase = (blockIdx.x * 4 + wave) * 16;
    if (nbase >= N) return;
    const int g = lane >> 4, c = lane & 15;

    int rowc = nbase + c; if (rowc >= N) rowc = N - 1;
    const unsigned short* arow = A + (size_t)rowc * DIN + g * 8;
    short8 afr[KK];
#pragma unroll
    for (int kk = 0; kk < KK; ++kk)
        afr[kk] = *(const short8*)(arow + kk * 32);

#pragma unroll
    for (int cc = 0; cc < 4; ++cc) {
        const float bev = b[cc * 16 + c];
        f32x4 acc = {bev, bev, bev, bev};
#pragma unroll
        for (int kk = 0; kk < KK; ++kk) {
            short8 bw = *(const short8*)(W + (size_t)(cc * 16 + c) * DIN + kk * 32 + g * 8);
            acc = __builtin_amdgcn_mfma_f32_16x16x32_bf16(afr[kk], bw, acc, 0, 0, 0);
        }
#pragma unroll
        for (int r = 0; r < 4; ++r) {
            int row = nbase + g * 4 + r;
            if (row < N) out[(size_t)row * 64 + cc * 16 + c] = acc[r];
        }
    }
}

// ---------------------------------------------------------------------------
// Node-tile MFMA GEMM with fused BN+relu on the A side:
//   h[n][k] = relu(t[n][k]*sc[k]+sh[k])  (bf16)
//   out[n][f] = b2[f] + h[n] . W2[f]     (+optional relu + bf16 emit)
// ---------------------------------------------------------------------------
__global__ __launch_bounds__(256) void ngemm_bn_kernel(
    const float* __restrict__ t, const float* __restrict__ scsh,
    const short* __restrict__ W2, const float* __restrict__ b2,
    float* __restrict__ out, unsigned short* __restrict__ outb,
    int N, int relu_out)
{
    const int wave = threadIdx.x >> 6;
    const int lane = threadIdx.x & 63;
    const int nbase = (blockIdx.x * 4 + wave) * 16;
    if (nbase >= N) return;
    const int g = lane >> 4, c = lane & 15;

    int rowc = nbase + c; if (rowc >= N) rowc = N - 1;
    const float* trow = t + (size_t)rowc * 64 + g * 8;

    short8 afr[2];
#pragma unroll
    for (int kk = 0; kk < 2; ++kk) {
        f32x4 q0 = *(const f32x4*)(trow + kk * 32);
        f32x4 q1 = *(const f32x4*)(trow + kk * 32 + 4);
        const int kbase = kk * 32 + g * 8;
        f32x4 sc0 = *(const f32x4*)(scsh + kbase);
        f32x4 sc1 = *(const f32x4*)(scsh + kbase + 4);
        f32x4 sh0 = *(const f32x4*)(scsh + 64 + kbase);
        f32x4 sh1 = *(const f32x4*)(scsh + 64 + kbase + 4);
#pragma unroll
        for (int j = 0; j < 4; ++j) {
            afr[kk][j]     = f2bf(fmaxf(q0[j] * sc0[j] + sh0[j], 0.f));
            afr[kk][j + 4] = f2bf(fmaxf(q1[j] * sc1[j] + sh1[j], 0.f));
        }
    }

#pragma unroll
    for (int cc = 0; cc < 4; ++cc) {
        const float bev = b2[cc * 16 + c];
        f32x4 acc = {bev, bev, bev, bev};
#pragma unroll
        for (int kk = 0; kk < 2; ++kk) {
            short8 bw = *(const short8*)(W2 + (size_t)(cc * 16 + c) * 64 + kk * 32 + g * 8);
            acc = __builtin_amdgcn_mfma_f32_16x16x32_bf16(afr[kk], bw, acc, 0, 0, 0);
        }
#pragma unroll
        for (int r = 0; r < 4; ++r) {
            int row = nbase + g * 4 + r;
            if (row < N) {
                float v = acc[r];
                if (relu_out) {
                    v = fmaxf(v, 0.f);
                    outb[(size_t)row * 64 + cc * 16 + c] = (unsigned short)f2bf(v);
                }
                out[(size_t)row * 64 + cc * 16 + c] = v;
            }
        }
    }
}

// ---------------------------------------------------------------------------
// L0 gather (pure streaming): t[n][f] = xw1[n][f] + sum_i pbuf[i][f]
// ---------------------------------------------------------------------------
__global__ __launch_bounds__(256) void gather0_kernel(
    const unsigned short* __restrict__ pbuf,
    const int* __restrict__ offs,
    const float* __restrict__ xw1, float* __restrict__ t, int N)
{
    int wid = threadIdx.x >> 6, lane = threadIdx.x & 63;
    int n = blockIdx.x * 4 + wid;
    if (n >= N) return;
    float acc = xw1[(size_t)n * 64 + lane];
    int i0 = offs[n], i1 = offs[n + 1];
    const unsigned short* p = pbuf + (size_t)i0 * 64 + lane;
    int cnt = i1 - i0;
    int i = 0;
    for (; i + 3 < cnt; i += 4) {
        acc += bf2f(p[0]) + bf2f(p[64]) + bf2f(p[128]) + bf2f(p[192]);
        p += 256;
    }
    for (; i < cnt; ++i) { acc += bf2f(p[0]); p += 64; }
    t[(size_t)n * 64 + lane] = acc;
}

// ---------------------------------------------------------------------------
// L1 gather-sum (pure streaming): sb[n][k] = bf16(y0[n][k] + sum_i pbuf[i][k])
// ---------------------------------------------------------------------------
__global__ __launch_bounds__(256) void gathersum1_kernel(
    const unsigned short* __restrict__ pbuf,
    const int* __restrict__ offs,
    const float* __restrict__ y0, unsigned short* __restrict__ sb, int N)
{
    int wid = threadIdx.x >> 6, lane = threadIdx.x & 63;
    int n = blockIdx.x * 4 + wid;
    if (n >= N) return;
    float s = y0[(size_t)n * 64 + lane];
    int i0 = offs[n], i1 = offs[n + 1];
    const unsigned short* p = pbuf + (size_t)i0 * 64 + lane;
    int cnt = i1 - i0;
    int i = 0;
    for (; i + 3 < cnt; i += 4) {
        s += bf2f(p[0]) + bf2f(p[64]) + bf2f(p[128]) + bf2f(p[192]);
        p += 256;
    }
    for (; i < cnt; ++i) { s += bf2f(p[0]); p += 64; }
    sb[(size_t)n * 64 + lane] = (unsigned short)f2bf(s);
}

// ---------------------------------------------------------------------------
// BN stats + final
// ---------------------------------------------------------------------------
__global__ __launch_bounds__(256) void bnstats_kernel(
    const float* __restrict__ t, float* __restrict__ sums, int total)
{
    int tid = threadIdx.x;
    float s = 0.f, s2 = 0.f;
    for (int i = blockIdx.x * 256 + tid; i < total; i += gridDim.x * 256) {
        float v = t[i];
        s += v; s2 += v * v;
    }
    __shared__ float ls[256], ls2[256];
    ls[tid] = s; ls2[tid] = s2;
    __syncthreads();
    if (tid < 64) {
        s  = ls[tid]  + ls[tid + 64]  + ls[tid + 128]  + ls[tid + 192];
        s2 = ls2[tid] + ls2[tid + 64] + ls2[tid + 128] + ls2[tid + 192];
        atomicAdd(&sums[tid], s);
        atomicAdd(&sums[64 + tid], s2);
    }
}

__global__ void bnfinal_kernel(const float* __restrict__ sums,
                               const float* __restrict__ g,
                               const float* __restrict__ bb,
                               float* __restrict__ scsh, float invN)
{
    int f = threadIdx.x;  // 64 threads
    float mean = sums[f] * invN;
    float var  = sums[64 + f] * invN - mean * mean;
    float sc = g[f] * rsqrtf(var + 1e-5f);
    scsh[f] = sc;
    scsh[64 + f] = bb[f] - mean * sc;
}

// ---------------------------------------------------------------------------
// Weight prep: f32 -> bf16
// ---------------------------------------------------------------------------
__global__ __launch_bounds__(256) void prep_kernel(
    const float* __restrict__ We0, const float* __restrict__ W1_0,
    const float* __restrict__ We1, const float* __restrict__ W1_1,
    const float* __restrict__ W2_0, const float* __restrict__ W2_1,
    short* __restrict__ WeB0, short* __restrict__ W1B0,
    short* __restrict__ WeB1, short* __restrict__ W1B1,
    short* __restrict__ W2B0, short* __restrict__ W2B1)
{
    int i = blockIdx.x * 256 + threadIdx.x;
    if (i < 128 * 64) WeB0[i] = f2bf(We0[i]);
    if (i < 64 * 128) W1B0[i] = f2bf(W1_0[i]);
    if (i < 64 * 64) {
        WeB1[i] = f2bf(We1[i]);
        W1B1[i] = f2bf(W1_1[i]);
        W2B0[i] = f2bf(W2_0[i]);
        W2B1[i] = f2bf(W2_1[i]);
    }
}

extern "C" void kernel_launch(void* const* d_in, const int* in_sizes, int n_in,
                              void* d_out, int out_size, void* d_ws, size_t ws_size,
                              hipStream_t stream)
{
    (void)n_in; (void)out_size; (void)ws_size;
    const float* x     = (const float*)d_in[0];
    const int*   ei    = (const int*)d_in[1];
    const float* eattr = (const float*)d_in[2];
    const float* We0   = (const float*)d_in[3];
    const float* be0   = (const float*)d_in[4];
    const float* W1_0  = (const float*)d_in[5];
    const float* b1_0  = (const float*)d_in[6];
    const float* g0    = (const float*)d_in[7];
    const float* bb0   = (const float*)d_in[8];
    const float* W2_0  = (const float*)d_in[9];
    const float* b2_0  = (const float*)d_in[10];
    const float* We1   = (const float*)d_in[11];
    const float* be1   = (const float*)d_in[12];
    const float* W1_1  = (const float*)d_in[13];
    const float* b1_1  = (const float*)d_in[14];
    const float* g1    = (const float*)d_in[15];
    const float* bb1   = (const float*)d_in[16];
    const float* W2_1  = (const float*)d_in[17];
    const float* b2_1  = (const float*)d_in[18];
    float* out = (float*)d_out;

    const int N = in_sizes[0] / 128;   // 50000
    const int E = in_sizes[2] / 64;    // 800000

    char* ws = (char*)d_ws;
    size_t o = 0;
    auto alloc = [&](size_t bytes) { char* p = ws + o; o = (o + bytes + 255) & ~(size_t)255; return p; };
    unsigned short* pbuf = (unsigned short*)alloc((size_t)E * 64 * 2);
    float* tbuf   = (float*)alloc((size_t)N * 64 * 4);
    float* y0     = (float*)alloc((size_t)N * 64 * 4);   // also xw1 scratch (L0)
    unsigned short* xb = (unsigned short*)alloc((size_t)N * 128 * 2);
    unsigned short* yb = (unsigned short*)alloc((size_t)N * 64 * 2);  // also sb (L1)
    short* WeB0   = (short*)alloc(128 * 64 * 2);
    short* W1B0   = (short*)alloc(64 * 128 * 2);
    short* WeB1   = (short*)alloc(64 * 64 * 2);
    short* W1B1   = (short*)alloc(64 * 64 * 2);
    short* W2B0   = (short*)alloc(64 * 64 * 2);
    short* W2B1   = (short*)alloc(64 * 64 * 2);
    float* stats  = (float*)alloc(512 * 4);
    int*   cnt    = (int*)alloc((size_t)N * 4);
    int*   offs   = (int*)alloc((size_t)(N + 1) * 4);
    int*   inv    = (int*)alloc((size_t)E * 4);
    float* sum0  = stats;
    float* scsh0 = stats + 128;
    float* sum1  = stats + 256;
    float* scsh1 = stats + 384;
    float* xw1f  = y0;    // alias: consumed by gather0 before ngemm_bn writes y0
    unsigned short* sb = yb;  // alias: edge1 reads yb before gathersum1 writes sb

    hipMemsetAsync(stats, 0, 512 * 4, stream);
    hipMemsetAsync(cnt, 0, (size_t)N * 4, stream);
    prep_kernel<<<64, 256, 0, stream>>>(We0, W1_0, We1, W1_1, W2_0, W2_1,
                                        WeB0, W1B0, WeB1, W1B1, W2B0, W2B1);
    xcast_kernel<<<2048, 256, 0, stream>>>(x, xb, N * 128);

    const int eb256 = (E + 255) / 256;

    // ----- CSR by dst (offs) + edge -> sorted-position map (inv) -----
    hist_kernel<<<eb256, 256, 0, stream>>>(ei, cnt, E);
    scan_kernel<<<1, 1024, 0, stream>>>(cnt, offs, cnt, N);
    scatter_kernel<<<eb256, 256, 0, stream>>>(ei, cnt, inv, E);

    const int edge_blocks = (E + 63) / 64;
    const int n4_blocks   = (N + 3) / 4;
    const int nt_blocks   = ((N + 15) / 16 + 3) / 4;

    // ----- layer 0 -----
    edge2_kernel<128><<<edge_blocks, 256, 0, stream>>>(
        xb, ei, eattr, WeB0, be0, W1B0, inv, pbuf, E);
    ngemm_kernel<128><<<nt_blocks, 256, 0, stream>>>(xb, W1B0, b1_0, xw1f, N);
    gather0_kernel<<<n4_blocks, 256, 0, stream>>>(pbuf, offs, xw1f, tbuf, N);
    bnstats_kernel<<<256, 256, 0, stream>>>(tbuf, sum0, N * 64);
    bnfinal_kernel<<<1, 64, 0, stream>>>(sum0, g0, bb0, scsh0, 1.0f / N);
    ngemm_bn_kernel<<<nt_blocks, 256, 0, stream>>>(
        tbuf, scsh0, W2B0, b2_0, y0, yb, N, 1);

    // ----- layer 1 -----
    edge1_kernel<<<edge_blocks, 256, 0, stream>>>(
        yb, ei, eattr, WeB1, be1, inv, pbuf, E);
    gathersum1_kernel<<<n4_blocks, 256, 0, stream>>>(pbuf, offs, y0, sb, N);
    ngemm_kernel<64><<<nt_blocks, 256, 0, stream>>>(sb, W1B1, b1_1, tbuf, N);
    bnstats_kernel<<<256, 256, 0, stream>>>(tbuf, sum1, N * 64);
    bnfinal_kernel<<<1, 64, 0, stream>>>(sum1, g1, bb1, scsh1, 1.0f / N);
    ngemm_bn_kernel<<<nt_blocks, 256, 0, stream>>>(
        tbuf, scsh1, W2B1, b2_1, out, yb, N, 0);
}